// Round 2
// baseline (1025.258 us; speedup 1.0000x reference)
//
#include <hip/hip_runtime.h>
#include <math.h>

#define NN 100000
#define NE 3200000
#define FIN 512
#define HID 16
#define NC 40
#define KCHUNKS 4
#define KCH (FIN / KCHUNKS)   // 128

// -------------------------------------------------------------- init --------
// zero h1pre, deg = 1 (self loop)
__global__ __launch_bounds__(256) void k_init(float* __restrict__ h1pre,
                                              float* __restrict__ deg) {
    int i = blockIdx.x * 256 + threadIdx.x;
    if (i < NN * HID) h1pre[i] = 0.0f;
    if (i < NN) deg[i] = 1.0f;
}

__global__ __launch_bounds__(256) void k_deg_count(const int* __restrict__ dst,
                                                   float* __restrict__ deg) {
    int e = blockIdx.x * 256 + threadIdx.x;
    if (e < NE) atomicAdd(&deg[dst[e]], 1.0f);
}

__global__ __launch_bounds__(256) void k_dinv(float* __restrict__ deg) {
    int i = blockIdx.x * 256 + threadIdx.x;
    if (i < NN) deg[i] = rsqrtf(deg[i]);   // deg >= 1 always
}

// ----------------------------------------- layer1 partial (K-split) ---------
// h1pre[n][j] += sum_{k in chunk} x[n][k] * W1[j][k]
__global__ __launch_bounds__(256) void k_h2_partial(const float* __restrict__ x,
                                                    const float* __restrict__ W1,
                                                    float* __restrict__ h1pre) {
    __shared__ float xs[256 * 33];   // 256 rows x 32 cols, +1 pad
    const int t  = threadIdx.x;
    const int n0 = blockIdx.x * 256;
    const int n  = n0 + t;
    const int kbase = blockIdx.y * KCH;

    float acc[HID];
#pragma unroll
    for (int j = 0; j < HID; ++j) acc[j] = 0.0f;

    const int lrow = t >> 3;          // 0..31
    const int lcol = (t & 7) * 4;     // 0,4,...,28

    for (int kc = kbase; kc < kbase + KCH; kc += 32) {
        // cooperative, coalesced load of a 256x32 fp32 tile
#pragma unroll
        for (int pass = 0; pass < 8; ++pass) {
            int row = pass * 32 + lrow;
            int g = n0 + row;
            if (g > NN - 1) g = NN - 1;                 // clamp (safe re-read)
            const float4 v = *(const float4*)(x + (size_t)g * FIN + kc + lcol);
            xs[row * 33 + lcol + 0] = v.x;
            xs[row * 33 + lcol + 1] = v.y;
            xs[row * 33 + lcol + 2] = v.z;
            xs[row * 33 + lcol + 3] = v.w;
        }
        __syncthreads();
#pragma unroll
        for (int k = 0; k < 32; ++k) {
            const float xv = xs[t * 33 + k];
            const float* wp = W1 + kc + k;              // uniform across wave
#pragma unroll
            for (int j = 0; j < HID; ++j)
                acc[j] = fmaf(xv, wp[j * FIN], acc[j]);
        }
        __syncthreads();
    }

    if (n < NN) {
#pragma unroll
        for (int j = 0; j < HID; ++j)
            atomicAdd(&h1pre[(size_t)n * HID + j], acc[j]);
    }
}

// ------------------------------- epilogue: bias+relu, Wg, self-loop init ----
__global__ __launch_bounds__(256) void k_h2_epi(const float* __restrict__ h1pre,
                                                const float* __restrict__ b1,
                                                const float* __restrict__ Wg,
                                                const float* __restrict__ dinv,
                                                float* __restrict__ h2,
                                                float* __restrict__ agg) {
    int n = blockIdx.x * 256 + threadIdx.x;
    if (n >= NN) return;

    float h1[HID];
    const float4* pp = (const float4*)(h1pre + (size_t)n * HID);
#pragma unroll
    for (int q = 0; q < 4; ++q) {
        float4 a = pp[q];
        h1[4*q+0] = a.x; h1[4*q+1] = a.y; h1[4*q+2] = a.z; h1[4*q+3] = a.w;
    }
#pragma unroll
    for (int j = 0; j < HID; ++j) h1[j] = fmaxf(h1[j] + b1[j], 0.0f);

    float hv[HID];
#pragma unroll
    for (int f = 0; f < HID; ++f) {
        float s = 0.0f;
#pragma unroll
        for (int j = 0; j < HID; ++j) s = fmaf(h1[j], Wg[f * HID + j], s);
        hv[f] = s;
    }

    const float di = dinv[n];
    const float d2 = di * di;
    float4* hp = (float4*)(h2  + (size_t)n * HID);
    float4* ap = (float4*)(agg + (size_t)n * HID);
#pragma unroll
    for (int q = 0; q < 4; ++q) {
        float4 v = make_float4(hv[4*q+0], hv[4*q+1], hv[4*q+2], hv[4*q+3]);
        hp[q] = v;
        ap[q] = make_float4(v.x * d2, v.y * d2, v.z * d2, v.w * d2);
    }
}

// ------------------------------------------------------ edge scatter --------
// 16 lanes per edge: agg[dst][f] += h2[src][f] * dinv[src]*dinv[dst]
__global__ __launch_bounds__(256) void k_scatter(const int* __restrict__ esrc,
                                                 const int* __restrict__ edst,
                                                 const float* __restrict__ dinv,
                                                 const float* __restrict__ h2,
                                                 float* __restrict__ agg) {
    int t = blockIdx.x * 256 + threadIdx.x;    // NE*16 = 51.2M < 2^31
    if (t >= NE * HID) return;
    int e = t >> 4;
    int f = t & 15;
    int s = esrc[e];
    int d = edst[e];
    float nrm = dinv[s] * dinv[d];
    atomicAdd(&agg[(size_t)d * HID + f], h2[(size_t)s * HID + f] * nrm);
}

// --------------------------------------- classifier + log_softmax -----------
__global__ __launch_bounds__(256) void k_final(const float* __restrict__ agg,
                                               const float* __restrict__ bg,
                                               const float* __restrict__ W2,
                                               const float* __restrict__ b2,
                                               float* __restrict__ out) {
    int n = blockIdx.x * 256 + threadIdx.x;
    if (n >= NN) return;

    float v[HID];
    const float4* ap = (const float4*)(agg + (size_t)n * HID);
#pragma unroll
    for (int q = 0; q < 4; ++q) {
        float4 a = ap[q];
        v[4*q+0] = a.x; v[4*q+1] = a.y; v[4*q+2] = a.z; v[4*q+3] = a.w;
    }
#pragma unroll
    for (int j = 0; j < HID; ++j) v[j] = fmaxf(v[j] + bg[j], 0.0f);

    float lg[NC];
    float m = -1e30f;
#pragma unroll
    for (int c = 0; c < NC; ++c) {
        float s = b2[c];
#pragma unroll
        for (int j = 0; j < HID; ++j) s = fmaf(v[j], W2[c * HID + j], s);
        lg[c] = s;
        m = fmaxf(m, s);
    }
    float se = 0.0f;
#pragma unroll
    for (int c = 0; c < NC; ++c) se += expf(lg[c] - m);
    const float lse = m + logf(se);

    float4* op = (float4*)(out + (size_t)n * NC);
#pragma unroll
    for (int q = 0; q < NC / 4; ++q)
        op[q] = make_float4(lg[4*q+0] - lse, lg[4*q+1] - lse,
                            lg[4*q+2] - lse, lg[4*q+3] - lse);
}

// ---------------------------------------------------------------- launch ----
extern "C" void kernel_launch(void* const* d_in, const int* in_sizes, int n_in,
                              void* d_out, int out_size, void* d_ws, size_t ws_size,
                              hipStream_t stream) {
    const float* x   = (const float*)d_in[0];
    const int*   ei  = (const int*)d_in[1];     // [2, NE] int32
    const float* W1  = (const float*)d_in[2];
    const float* b1  = (const float*)d_in[3];
    const float* Wg  = (const float*)d_in[4];
    const float* bg  = (const float*)d_in[5];
    const float* W2  = (const float*)d_in[6];
    const float* b2  = (const float*)d_in[7];
    float*       out = (float*)d_out;

    const int* esrc = ei;
    const int* edst = ei + NE;

    // workspace (fp32): deg/dinv [NN] | h1pre [NN*16] | h2 [NN*16] | agg [NN*16]
    float* deg   = (float*)d_ws;
    float* h1pre = deg + NN;
    float* h2    = h1pre + (size_t)NN * HID;
    float* agg   = h2 + (size_t)NN * HID;

    const int nodeBlocks = (NN + 255) / 256;        // 391
    const int edgeBlocks = (NE + 255) / 256;        // 12500
    const int scatBlocks = (NE * HID + 255) / 256;  // 200000
    const int initBlocks = (NN * HID + 255) / 256;  // 6250

    k_init<<<initBlocks, 256, 0, stream>>>(h1pre, deg);
    k_deg_count<<<edgeBlocks, 256, 0, stream>>>(edst, deg);
    k_dinv<<<nodeBlocks, 256, 0, stream>>>(deg);
    k_h2_partial<<<dim3(nodeBlocks, KCHUNKS), 256, 0, stream>>>(x, W1, h1pre);
    k_h2_epi<<<nodeBlocks, 256, 0, stream>>>(h1pre, b1, Wg, deg, h2, agg);
    k_scatter<<<scatBlocks, 256, 0, stream>>>(esrc, edst, deg, h2, agg);
    k_final<<<nodeBlocks, 256, 0, stream>>>(agg, bg, W2, b2, out);
}

// Round 3
// 739.510 us; speedup vs baseline: 1.3864x; 1.3864x over previous
//
#include <hip/hip_runtime.h>
#include <math.h>

#define NN 100000
#define NE 3200000
#define FIN 512
#define HID 16
#define NC 40

typedef short bf16x8 __attribute__((ext_vector_type(8)));
typedef float f32x4  __attribute__((ext_vector_type(4)));

__device__ inline short bf1(float f) {            // fp32 -> bf16 RNE
    unsigned u = __float_as_uint(f);
    unsigned r = (u + 0x7fffu + ((u >> 16) & 1u)) >> 16;
    return (short)r;
}
__device__ inline bf16x8 pack8(float4 a, float4 b) {
    bf16x8 r;
    r[0] = bf1(a.x); r[1] = bf1(a.y); r[2] = bf1(a.z); r[3] = bf1(a.w);
    r[4] = bf1(b.x); r[5] = bf1(b.y); r[6] = bf1(b.z); r[7] = bf1(b.w);
    return r;
}

// ------------------------------------------------------------ CSR build -----
__global__ __launch_bounds__(256) void k_zero(int* __restrict__ cnt) {
    int i = blockIdx.x * 256 + threadIdx.x;
    if (i < NN) cnt[i] = 0;
}

__global__ __launch_bounds__(256) void k_hist(const int* __restrict__ dst,
                                              int* __restrict__ cnt) {
    int e = blockIdx.x * 256 + threadIdx.x;
    if (e < NE) atomicAdd(&cnt[dst[e]], 1);
}

__global__ __launch_bounds__(256) void k_dinv(const int* __restrict__ cnt,
                                              float* __restrict__ dinv) {
    int i = blockIdx.x * 256 + threadIdx.x;
    if (i < NN) dinv[i] = rsqrtf(1.0f + (float)cnt[i]);   // +1 self loop
}

// block-local inclusive scan of cnt -> sc, block totals -> bsum
__global__ __launch_bounds__(256) void k_sc1(const int* __restrict__ cnt,
                                             int* __restrict__ sc,
                                             int* __restrict__ bsum) {
    __shared__ int s[256];
    int t = threadIdx.x, i = blockIdx.x * 256 + t;
    int v = (i < NN) ? cnt[i] : 0;
    s[t] = v; __syncthreads();
#pragma unroll
    for (int off = 1; off < 256; off <<= 1) {
        int a = (t >= off) ? s[t - off] : 0;
        __syncthreads();
        s[t] += a;
        __syncthreads();
    }
    if (i < NN) sc[i] = s[t];
    if (t == 255) bsum[blockIdx.x] = s[t];
}

// scan the 391 block totals -> exclusive bpre (one block of 512)
__global__ __launch_bounds__(512) void k_sc2(const int* __restrict__ bsum,
                                             int* __restrict__ bpre,
                                             int nblk) {
    __shared__ int s[512];
    int t = threadIdx.x;
    int v = (t < nblk) ? bsum[t] : 0;
    s[t] = v; __syncthreads();
#pragma unroll
    for (int off = 1; off < 512; off <<= 1) {
        int a = (t >= off) ? s[t - off] : 0;
        __syncthreads();
        s[t] += a;
        __syncthreads();
    }
    if (t < nblk) bpre[t] = s[t] - v;   // exclusive
}

// offs = exclusive scan; zero sc for reuse as placement counters
__global__ __launch_bounds__(256) void k_sc3(const int* __restrict__ cnt,
                                             int* __restrict__ sc,
                                             const int* __restrict__ bpre,
                                             int* __restrict__ offs) {
    int i = blockIdx.x * 256 + threadIdx.x;
    if (i < NN) {
        offs[i] = sc[i] - cnt[i] + bpre[i >> 8];
        sc[i] = 0;
    }
    if (i == 0) offs[NN] = NE;
}

__global__ __launch_bounds__(256) void k_place(const int* __restrict__ src,
                                               const int* __restrict__ dst,
                                               const int* __restrict__ offs,
                                               int* __restrict__ ctr,
                                               int* __restrict__ ssrc) {
    int e = blockIdx.x * 256 + threadIdx.x;
    if (e >= NE) return;
    int d = dst[e];
    int r = atomicAdd(&ctr[d], 1);
    ssrc[offs[d] + r] = src[e];
}

// ------------------------------------- layer1+Wg: per-wave MFMA GEMM --------
// wave handles 16 nodes: h1 = relu(x@W1^T + b1) via 16 MFMAs (K=512),
// then h2 = h1@Wg^T via one more MFMA after an in-wave LDS transpose.
__global__ __launch_bounds__(256) void k_h2(const float* __restrict__ x,
                                            const float* __restrict__ W1,
                                            const float* __restrict__ b1,
                                            const float* __restrict__ Wg,
                                            float* __restrict__ h2) {
    const int lane = threadIdx.x & 63;
    const int wv   = threadIdx.x >> 6;          // 0..3
    const int c    = lane & 15;                 // A row / B col
    const int q    = lane >> 4;                 // 0..3
    const int n0   = blockIdx.x * 64 + wv * 16;

    // B frags: lane holds B[k=(kk*32)+q*8+i][n=c] = W1[c][kk*32+q*8+i]
    bf16x8 bf[16];
    const float* wrow = W1 + c * FIN;
#pragma unroll
    for (int kk = 0; kk < 16; ++kk) {
        const float4* p = (const float4*)(wrow + kk * 32 + q * 8);
        bf[kk] = pack8(p[0], p[1]);
    }
    // Wg frag (K padded 16->32 with zeros): B2[k=j][n=c] = Wg[c][j]
    bf16x8 gf = {0,0,0,0,0,0,0,0};
    if (q < 2) {
        const float4* p = (const float4*)(Wg + c * HID + q * 8);
        gf = pack8(p[0], p[1]);
    }

    f32x4 acc = {0.f, 0.f, 0.f, 0.f};
    int na = n0 + c; if (na > NN - 1) na = NN - 1;   // clamp (stores masked)
    const float* xr = x + (size_t)na * FIN + q * 8;
#pragma unroll 4
    for (int kk = 0; kk < 16; ++kk) {
        const float4* p = (const float4*)(xr + kk * 32);
        bf16x8 af = pack8(p[0], p[1]);
        acc = __builtin_amdgcn_mfma_f32_16x16x32_bf16(af, bf[kk], acc, 0, 0, 0);
    }

    // acc[r] = h1pre[node n0+q*4+r][j=c]; bias+relu; transpose via LDS (bf16)
    __shared__ __align__(16) short tl[4][16][16];
    const float bj = b1[c];
#pragma unroll
    for (int r = 0; r < 4; ++r)
        tl[wv][q * 4 + r][c] = bf1(fmaxf(acc[r] + bj, 0.f));
    __syncthreads();

    bf16x8 a2 = {0,0,0,0,0,0,0,0};
    if (q < 2) a2 = *(const bf16x8*)&tl[wv][c][q * 8];   // A2[m=c][k=j]
    f32x4 z = {0.f, 0.f, 0.f, 0.f};
    f32x4 o = __builtin_amdgcn_mfma_f32_16x16x32_bf16(a2, gf, z, 0, 0, 0);
#pragma unroll
    for (int r = 0; r < 4; ++r) {
        int node = n0 + q * 4 + r;
        if (node < NN) h2[node * HID + c] = o[r];
    }
}

// ---------------------------------------------- CSR gather (no atomics) -----
// 16 lanes per node; lane f accumulates feature f over the node's src list.
__global__ __launch_bounds__(256) void k_gather(const int* __restrict__ offs,
                                                const int* __restrict__ ssrc,
                                                const float* __restrict__ dinv,
                                                const float* __restrict__ h2,
                                                float* __restrict__ hagg) {
    int t = threadIdx.x;
    int n = blockIdx.x * 16 + (t >> 4);
    int f = t & 15;
    if (n >= NN) return;
    const float di = dinv[n];
    float acc = h2[n * HID + f] * di * di;      // self loop
    const int e0 = offs[n], e1 = offs[n + 1];
    for (int e = e0; e < e1; ++e) {
        int s = ssrc[e];
        acc += h2[s * HID + f] * (dinv[s] * di);
    }
    hagg[n * HID + f] = acc;
}

// --------------------------------------------------- fallback (atomics) -----
__global__ __launch_bounds__(256) void k_agg_init(const float* __restrict__ h2,
                                                  const float* __restrict__ dinv,
                                                  float* __restrict__ hagg) {
    int i = blockIdx.x * 256 + threadIdx.x;
    if (i >= NN * HID) return;
    float di = dinv[i >> 4];
    hagg[i] = h2[i] * di * di;
}

__global__ __launch_bounds__(256) void k_scatter(const int* __restrict__ esrc,
                                                 const int* __restrict__ edst,
                                                 const float* __restrict__ dinv,
                                                 const float* __restrict__ h2,
                                                 float* __restrict__ hagg) {
    int t = blockIdx.x * 256 + threadIdx.x;
    if (t >= NE * HID) return;
    int e = t >> 4, f = t & 15;
    int s = esrc[e], d = edst[e];
    float nrm = dinv[s] * dinv[d];
    atomicAdd(&hagg[(size_t)d * HID + f], h2[(size_t)s * HID + f] * nrm);
}

// --------------------------------------- classifier + log_softmax -----------
__global__ __launch_bounds__(256) void k_final(const float* __restrict__ hagg,
                                               const float* __restrict__ bg,
                                               const float* __restrict__ W2,
                                               const float* __restrict__ b2,
                                               float* __restrict__ out) {
    int n = blockIdx.x * 256 + threadIdx.x;
    if (n >= NN) return;

    float v[HID];
    const float4* ap = (const float4*)(hagg + (size_t)n * HID);
#pragma unroll
    for (int qq = 0; qq < 4; ++qq) {
        float4 a = ap[qq];
        v[4*qq+0] = a.x; v[4*qq+1] = a.y; v[4*qq+2] = a.z; v[4*qq+3] = a.w;
    }
#pragma unroll
    for (int j = 0; j < HID; ++j) v[j] = fmaxf(v[j] + bg[j], 0.0f);

    float lg[NC];
    float m = -1e30f;
#pragma unroll
    for (int cc = 0; cc < NC; ++cc) {
        float s = b2[cc];
#pragma unroll
        for (int j = 0; j < HID; ++j) s = fmaf(v[j], W2[cc * HID + j], s);
        lg[cc] = s;
        m = fmaxf(m, s);
    }
    float se = 0.0f;
#pragma unroll
    for (int cc = 0; cc < NC; ++cc) se += expf(lg[cc] - m);
    const float lse = m + logf(se);

    float4* op = (float4*)(out + (size_t)n * NC);
#pragma unroll
    for (int qq = 0; qq < NC / 4; ++qq)
        op[qq] = make_float4(lg[4*qq+0] - lse, lg[4*qq+1] - lse,
                             lg[4*qq+2] - lse, lg[4*qq+3] - lse);
}

// ---------------------------------------------------------------- launch ----
extern "C" void kernel_launch(void* const* d_in, const int* in_sizes, int n_in,
                              void* d_out, int out_size, void* d_ws, size_t ws_size,
                              hipStream_t stream) {
    const float* x   = (const float*)d_in[0];
    const int*   ei  = (const int*)d_in[1];     // [2, NE] int32
    const float* W1  = (const float*)d_in[2];
    const float* b1  = (const float*)d_in[3];
    const float* Wg  = (const float*)d_in[4];
    const float* bg  = (const float*)d_in[5];
    const float* W2  = (const float*)d_in[6];
    const float* b2  = (const float*)d_in[7];
    float*       out = (float*)d_out;

    const int* esrc = ei;
    const int* edst = ei + NE;

    // ws layout (4B elems): cnt[NN] dinv[NN] h2[16NN] hagg[16NN] | sc[NN]
    //                       offs[NN+1] bsum[512] bpre[512] ssrc[NE]
    int*   cnt  = (int*)d_ws;
    float* dinv = (float*)(cnt + NN);
    float* h2   = dinv + NN;
    float* hagg = h2 + (size_t)NN * HID;
    int*   sc   = (int*)(hagg + (size_t)NN * HID);
    int*   offs = sc + NN;
    int*   bsum = offs + NN + 1;
    int*   bpre = bsum + 512;
    int*   ssrc = bpre + 512;
    const size_t need_csr = (size_t)(36 * NN + 1025 + NE) * 4;

    const int nodeBlocks = (NN + 255) / 256;        // 391
    const int edgeBlocks = (NE + 255) / 256;        // 12500
    const int h2Blocks   = (NN + 63) / 64;          // 1563
    const int gatBlocks  = (NN + 15) / 16;          // 6250

    k_zero<<<nodeBlocks, 256, 0, stream>>>(cnt);
    k_hist<<<edgeBlocks, 256, 0, stream>>>(edst, cnt);
    k_dinv<<<nodeBlocks, 256, 0, stream>>>(cnt, dinv);
    k_h2<<<h2Blocks, 256, 0, stream>>>(x, W1, b1, Wg, h2);

    if (ws_size >= need_csr) {
        k_sc1<<<nodeBlocks, 256, 0, stream>>>(cnt, sc, bsum);
        k_sc2<<<1, 512, 0, stream>>>(bsum, bpre, nodeBlocks);
        k_sc3<<<nodeBlocks, 256, 0, stream>>>(cnt, sc, bpre, offs);
        k_place<<<edgeBlocks, 256, 0, stream>>>(esrc, edst, offs, sc, ssrc);
        k_gather<<<gatBlocks, 256, 0, stream>>>(offs, ssrc, dinv, h2, hagg);
    } else {
        const int initBlocks = (NN * HID + 255) / 256;
        const int scatBlocks = (NE * HID + 255) / 256;
        k_agg_init<<<initBlocks, 256, 0, stream>>>(h2, dinv, hagg);
        k_scatter<<<scatBlocks, 256, 0, stream>>>(esrc, edst, dinv, h2, hagg);
    }
    k_final<<<nodeBlocks, 256, 0, stream>>>(hagg, bg, W2, b2, out);
}